// Round 6
// baseline (394.381 us; speedup 1.0000x reference)
//
#include <hip/hip_runtime.h>

namespace {
constexpr int kB = 16;
constexpr int kN = 131072;            // 2^17
constexpr int kNLog = 17;
constexpr int kCMid = 128;
constexpr int kCOut = 16;
constexpr int kCells32Log = 15;       // 32^3
constexpr int kCells64Log = 18;       // 64^3
constexpr int kCells32 = 1 << kCells32Log;
constexpr int kCells64 = 1 << kCells64Log;
constexpr long kOut32Elems = (long)kB * kCOut * kCells32;
constexpr long kWinnerU4 = (long)kB * (kCells32 + kCells64) / 4;  // 1,179,648 uint4
}  // namespace

__device__ inline unsigned int packbf2(float lo, float hi) {
    // RNE-round both to bf16, pack (hi<<16)|lo.
    unsigned int a = __float_as_uint(lo);
    unsigned int b = __float_as_uint(hi);
    a = (a + 0x7FFFu + ((a >> 16) & 1u)) >> 16;
    b = (b + 0x7FFFu + ((b >> 16) & 1u)) & 0xFFFF0000u;
    return b | a;
}
__device__ inline float bf_lo(unsigned int p) { return __uint_as_float(p << 16); }
__device__ inline float bf_hi(unsigned int p) { return __uint_as_float(p & 0xFFFF0000u); }

// ---------------------------------------------------------------------------
// Zero both winner arrays. Replaces hipMemsetAsync, whose runtime fill kernel
// ran at 180 us / 10% occupancy per replay (R5 rocprof). Grid-stride uint4.
// ---------------------------------------------------------------------------
__global__ __launch_bounds__(256) void zero_winners(uint4* __restrict__ p)
{
    const long stride = (long)gridDim.x * 256;
    for (long idx = (long)blockIdx.x * 256 + threadIdx.x; idx < kWinnerU4; idx += stride)
        p[idx] = make_uint4(0u, 0u, 0u, 0u);
}

// ---------------------------------------------------------------------------
// Stage packed weights: W1p[k][4] = (w0,w1,w2,b1k); W2t[k][16] (transposed).
// Loop-uniform float4 reads -> s_load broadcasts (verified R3/R4: SGPR 80-96).
// ---------------------------------------------------------------------------
__global__ __launch_bounds__(256) void pack_weights(
    const float* __restrict__ W1, const float* __restrict__ b1,
    const float* __restrict__ W2,
    float* __restrict__ W1p, float* __restrict__ W2t)
{
    const int t = threadIdx.x;
    for (int k = t; k < kCMid; k += 256) {
        W1p[k * 4 + 0] = W1[k * 3 + 0];
        W1p[k * 4 + 1] = W1[k * 3 + 1];
        W1p[k * 4 + 2] = W1[k * 3 + 2];
        W1p[k * 4 + 3] = b1[k];
    }
    for (int idx = t; idx < kCOut * kCMid; idx += 256) {
        const int c = idx >> 7;
        const int k = idx & 127;
        W2t[k * kCOut + c] = W2[idx];
    }
}

// ---------------------------------------------------------------------------
// Scatter only: per permuted position (b,i): j=perm, gather x[b,j], compute
// both cell ids, atomicMax(winner, i+1). Latency/atomic-bound; isolated so
// its stalls don't pollute the VALU-bound MLP kernel.
// Cell math: __fmul_rn/__fadd_rn (no FMA contraction) to match numpy
// truncation boundaries exactly.
// ---------------------------------------------------------------------------
__global__ __launch_bounds__(256, 4) void scatter_winners(
    const float* __restrict__ x,
    const int* __restrict__ perm,
    unsigned int* __restrict__ win32, unsigned int* __restrict__ win64)
{
    const long gid = (long)blockIdx.x * 256 + threadIdx.x;  // over B*N
    const int b = (int)(gid >> kNLog);
    const int i = (int)(gid & (kN - 1));
    const int j = perm[gid];

    const float* xp = x + ((long)b * kN + j) * 3;
    const float v0 = xp[0], v1 = xp[1], v2 = xp[2];

    const int ix32 = (int)fminf(fmaxf(__fadd_rn(__fmul_rn(v0, 32.0f), 16.5f), 0.0f), 31.0f);
    const int iy32 = (int)fminf(fmaxf(__fadd_rn(__fmul_rn(v1, 32.0f), 16.5f), 0.0f), 31.0f);
    const int iz32 = (int)fminf(fmaxf(__fadd_rn(__fmul_rn(v2, 32.0f), 16.5f), 0.0f), 31.0f);
    const int ix64 = (int)fminf(fmaxf(__fadd_rn(__fmul_rn(v0, 64.0f), 32.5f), 0.0f), 63.0f);
    const int iy64 = (int)fminf(fmaxf(__fadd_rn(__fmul_rn(v1, 64.0f), 32.5f), 0.0f), 63.0f);
    const int iz64 = (int)fminf(fmaxf(__fadd_rn(__fmul_rn(v2, 64.0f), 32.5f), 0.0f), 63.0f);

    const unsigned int pri = (unsigned int)(i + 1);
    atomicMax(&win32[b * kCells32 + (ix32 * 32 + iy32) * 32 + iz32], pri);
    atomicMax(&win64[b * kCells64 + (ix64 * 64 + iy64) * 64 + iz64], pri);
}

// ---------------------------------------------------------------------------
// Dense MLP in NATURAL point order, 2 points/thread:
//   coalesced 24B x reads, full 3->128->16 MLP (weights via uniform s_load),
//   store feat_nat[b,j] as 16 bf16 (32B) -- 64B contiguous per thread.
// No perm, no atomics, no gathers: pure VALU + streaming write.
// ---------------------------------------------------------------------------
__global__ __launch_bounds__(256, 4) void mlp_natural(
    const float* __restrict__ x,
    const float* __restrict__ W1p, const float* __restrict__ W2t,
    const float* __restrict__ b2,
    uint4* __restrict__ feat)          // 2 uint4 per point
{
    const long pair = (long)blockIdx.x * 256 + threadIdx.x;  // over B*N/2
    const long p0 = pair * 2;

    const float2 xa = *(const float2*)(x + p0 * 3 + 0);
    const float2 xb = *(const float2*)(x + p0 * 3 + 2);
    const float2 xc = *(const float2*)(x + p0 * 3 + 4);
    const float x00 = xa.x, x01 = xa.y, x02 = xb.x;
    const float x10 = xb.y, x11 = xc.x, x12 = xc.y;

    float acc0[kCOut], acc1[kCOut];
    #pragma unroll
    for (int c = 0; c < kCOut; ++c) { acc0[c] = 0.0f; acc1[c] = 0.0f; }

    const float4* __restrict__ w1v = (const float4*)W1p;
    const float4* __restrict__ w2v = (const float4*)W2t;

    #pragma unroll 4
    for (int k = 0; k < kCMid; ++k) {
        const float4 w1 = w1v[k];                        // uniform -> s_load
        const float h0 = fmaxf(fmaf(w1.x, x00, fmaf(w1.y, x01, fmaf(w1.z, x02, w1.w))), 0.0f);
        const float h1 = fmaxf(fmaf(w1.x, x10, fmaf(w1.y, x11, fmaf(w1.z, x12, w1.w))), 0.0f);
        #pragma unroll
        for (int q = 0; q < 4; ++q) {
            const float4 wq = w2v[k * 4 + q];            // uniform -> s_load
            acc0[4 * q + 0] = fmaf(wq.x, h0, acc0[4 * q + 0]);
            acc0[4 * q + 1] = fmaf(wq.y, h0, acc0[4 * q + 1]);
            acc0[4 * q + 2] = fmaf(wq.z, h0, acc0[4 * q + 2]);
            acc0[4 * q + 3] = fmaf(wq.w, h0, acc0[4 * q + 3]);
            acc1[4 * q + 0] = fmaf(wq.x, h1, acc1[4 * q + 0]);
            acc1[4 * q + 1] = fmaf(wq.y, h1, acc1[4 * q + 1]);
            acc1[4 * q + 2] = fmaf(wq.z, h1, acc1[4 * q + 2]);
            acc1[4 * q + 3] = fmaf(wq.w, h1, acc1[4 * q + 3]);
        }
    }

    const float4 bq0 = ((const float4*)b2)[0];
    const float4 bq1 = ((const float4*)b2)[1];
    const float4 bq2 = ((const float4*)b2)[2];
    const float4 bq3 = ((const float4*)b2)[3];

    uint4 f;
    f.x = packbf2(acc0[0]  + bq0.x, acc0[1]  + bq0.y);
    f.y = packbf2(acc0[2]  + bq0.z, acc0[3]  + bq0.w);
    f.z = packbf2(acc0[4]  + bq1.x, acc0[5]  + bq1.y);
    f.w = packbf2(acc0[6]  + bq1.z, acc0[7]  + bq1.w);
    feat[p0 * 2 + 0] = f;
    f.x = packbf2(acc0[8]  + bq2.x, acc0[9]  + bq2.y);
    f.y = packbf2(acc0[10] + bq2.z, acc0[11] + bq2.w);
    f.z = packbf2(acc0[12] + bq3.x, acc0[13] + bq3.y);
    f.w = packbf2(acc0[14] + bq3.z, acc0[15] + bq3.w);
    feat[p0 * 2 + 1] = f;
    f.x = packbf2(acc1[0]  + bq0.x, acc1[1]  + bq0.y);
    f.y = packbf2(acc1[2]  + bq0.z, acc1[3]  + bq0.w);
    f.z = packbf2(acc1[4]  + bq1.x, acc1[5]  + bq1.y);
    f.w = packbf2(acc1[6]  + bq1.z, acc1[7]  + bq1.w);
    feat[p0 * 2 + 2] = f;
    f.x = packbf2(acc1[8]  + bq2.x, acc1[9]  + bq2.y);
    f.y = packbf2(acc1[10] + bq2.z, acc1[11] + bq2.w);
    f.z = packbf2(acc1[12] + bq3.x, acc1[13] + bq3.y);
    f.w = packbf2(acc1[14] + bq3.z, acc1[15] + bq3.w);
    feat[p0 * 2 + 3] = f;
}

// ---------------------------------------------------------------------------
// Per-cell gather: win -> i -> j=perm[b,i] -> feat_nat[b,j] (L2/L3-resident
// hops), expand bf16 -> f32, write all 16 channels (zeros if empty).
// Rewrites the full output every call.
// ---------------------------------------------------------------------------
template <int CLOG>
__global__ __launch_bounds__(256) void gather_cells(
    const unsigned int* __restrict__ win,
    const int* __restrict__ perm,
    const uint4* __restrict__ feat,
    float* __restrict__ out)
{
    constexpr int cells = 1 << CLOG;
    const long gid = (long)blockIdx.x * 256 + threadIdx.x;  // over B*cells
    const int b = (int)(gid >> CLOG);
    const int cell = (int)(gid & (cells - 1));
    const unsigned int w = win[gid];

    float v[kCOut];
    #pragma unroll
    for (int c = 0; c < kCOut; ++c) v[c] = 0.0f;

    if (w != 0u) {
        const int i = (int)(w - 1u);
        const int j = perm[((long)b << kNLog) + i];
        const long pidx = ((long)b << kNLog) + j;
        const uint4 f0 = feat[pidx * 2 + 0];
        const uint4 f1 = feat[pidx * 2 + 1];
        v[0]  = bf_lo(f0.x); v[1]  = bf_hi(f0.x);
        v[2]  = bf_lo(f0.y); v[3]  = bf_hi(f0.y);
        v[4]  = bf_lo(f0.z); v[5]  = bf_hi(f0.z);
        v[6]  = bf_lo(f0.w); v[7]  = bf_hi(f0.w);
        v[8]  = bf_lo(f1.x); v[9]  = bf_hi(f1.x);
        v[10] = bf_lo(f1.y); v[11] = bf_hi(f1.y);
        v[12] = bf_lo(f1.z); v[13] = bf_hi(f1.z);
        v[14] = bf_lo(f1.w); v[15] = bf_hi(f1.w);
    }

    float* op = out + (((long)b * kCOut) << CLOG) + cell;
    #pragma unroll
    for (int c = 0; c < kCOut; ++c) op[(long)c << CLOG] = v[c];
}

extern "C" void kernel_launch(void* const* d_in, const int* in_sizes, int n_in,
                              void* d_out, int out_size, void* d_ws, size_t ws_size,
                              hipStream_t stream)
{
    const float* x  = (const float*)d_in[0];
    const float* W1 = (const float*)d_in[1];
    const float* b1 = (const float*)d_in[2];
    const float* W2 = (const float*)d_in[3];
    const float* b2 = (const float*)d_in[4];
    const int* perm = (const int*)d_in[5];

    float* out32 = (float*)d_out;
    float* out64 = out32 + kOut32Elems;

    // ws layout: [W1p 2KB][W2t 8KB][pad->16KB][win32 2MB][win64 16.8MB][feat 67MB]
    float* W1p = (float*)d_ws;
    float* W2t = W1p + kCMid * 4;
    unsigned int* win32 = (unsigned int*)((char*)d_ws + 16384);
    unsigned int* win64 = win32 + (size_t)kB * kCells32;
    const size_t winnerBytes = (size_t)kB * (kCells32 + kCells64) * sizeof(unsigned int);
    uint4* feat = (uint4*)((char*)win32 + winnerBytes);

    const int nPtsBlocks  = (int)(((long)kB * kN) / 256);        // 8192
    const int nPairBlocks = (int)(((long)kB * kN) / 512);        // 4096
    const int n32Blocks   = (int)(((long)kB * kCells32) / 256);  // 2048
    const int n64Blocks   = (int)(((long)kB * kCells64) / 256);  // 16384
    dim3 blk(256);

    zero_winners<<<2048, blk, 0, stream>>>((uint4*)win32);
    pack_weights<<<1, 256, 0, stream>>>(W1, b1, W2, W1p, W2t);

    scatter_winners<<<nPtsBlocks, blk, 0, stream>>>(x, perm, win32, win64);
    mlp_natural<<<nPairBlocks, blk, 0, stream>>>(x, W1p, W2t, b2, feat);
    gather_cells<kCells32Log><<<n32Blocks, blk, 0, stream>>>(win32, perm, feat, out32);
    gather_cells<kCells64Log><<<n64Blocks, blk, 0, stream>>>(win64, perm, feat, out64);
}

// Round 7
// 307.440 us; speedup vs baseline: 1.2828x; 1.2828x over previous
//
#include <hip/hip_runtime.h>

namespace {
constexpr int kB = 16;
constexpr int kN = 131072;            // 2^17
constexpr int kNLog = 17;
constexpr int kCMid = 128;
constexpr int kCOut = 16;
constexpr int kCells32Log = 15;       // 32^3
constexpr int kCells64Log = 18;       // 64^3
constexpr int kCells32 = 1 << kCells32Log;
constexpr int kCells64 = 1 << kCells64Log;
constexpr long kOut32Elems = (long)kB * kCOut * kCells32;
// u64 winner words: 16*(32768+262144) = 4,718,592 -> 2,359,296 uint4
constexpr long kWinU4 = (long)kB * (kCells32 + kCells64) / 2;
}  // namespace

__device__ inline unsigned int packbf2(float lo, float hi) {
    // RNE-round both to bf16, pack (hi<<16)|lo.
    unsigned int a = __float_as_uint(lo);
    unsigned int b = __float_as_uint(hi);
    a = (a + 0x7FFFu + ((a >> 16) & 1u)) >> 16;
    b = (b + 0x7FFFu + ((b >> 16) & 1u)) & 0xFFFF0000u;
    return b | a;
}
__device__ inline float bf_lo(unsigned int p) { return __uint_as_float(p << 16); }
__device__ inline float bf_hi(unsigned int p) { return __uint_as_float(p & 0xFFFF0000u); }

// ---------------------------------------------------------------------------
// Zero both u64 winner arrays (37.7 MB), grid-stride uint4.
// ---------------------------------------------------------------------------
__global__ __launch_bounds__(256) void k_zero(uint4* __restrict__ p)
{
    const long stride = (long)gridDim.x * 256;
    for (long idx = (long)blockIdx.x * 256 + threadIdx.x; idx < kWinU4; idx += stride)
        p[idx] = make_uint4(0u, 0u, 0u, 0u);
}

// ---------------------------------------------------------------------------
// Invert the per-batch permutation: inv[b][perm[b][i]] = i. Bijection ->
// plain scattered stores, no atomics. Coalesced read, random 4B write
// (L2-resident: 512KB/batch).
// ---------------------------------------------------------------------------
__global__ __launch_bounds__(256) void k_inv(
    const int* __restrict__ perm, int* __restrict__ inv)
{
    const long gid = (long)blockIdx.x * 256 + threadIdx.x;  // over B*N
    const long bbase = gid & ~(long)(kN - 1);               // b*kN
    inv[bbase + perm[gid]] = (int)(gid & (kN - 1));
}

// ---------------------------------------------------------------------------
// Stage packed weights: W1p[k][4] = (w0,w1,w2,b1k); W2t[k][16] (transposed).
// Loop-uniform float4 reads -> s_load broadcasts (verified R3/R4).
// ---------------------------------------------------------------------------
__global__ __launch_bounds__(256) void k_pack(
    const float* __restrict__ W1, const float* __restrict__ b1,
    const float* __restrict__ W2,
    float* __restrict__ W1p, float* __restrict__ W2t)
{
    const int t = threadIdx.x;
    for (int k = t; k < kCMid; k += 256) {
        W1p[k * 4 + 0] = W1[k * 3 + 0];
        W1p[k * 4 + 1] = W1[k * 3 + 1];
        W1p[k * 4 + 2] = W1[k * 3 + 2];
        W1p[k * 4 + 3] = b1[k];
    }
    for (int idx = t; idx < kCOut * kCMid; idx += 256) {
        const int c = idx >> 7;
        const int k = idx & 127;
        W2t[k * kCOut + c] = W2[idx];
    }
}

// ---------------------------------------------------------------------------
// Fused NATURAL-order pass, 1 point/thread over (b,j):
//   coalesced x read (12B/lane), coalesced inv read -> pri = i+1;
//   both u64 atomicMax((pri<<32)|j) issued BEFORE the MLP so the atomic
//   drain hides under the FMA stream (R4 evidence: fusion -> max not sum);
//   full 3->128->16 MLP (weights uniform s_load); feat[b,j] bf16 store 32B.
// Cell math: __fmul_rn/__fadd_rn (no FMA contraction) matches numpy exactly.
// ---------------------------------------------------------------------------
__global__ __launch_bounds__(256) void k_fused(
    const float* __restrict__ x,
    const int* __restrict__ inv,
    const float* __restrict__ W1p, const float* __restrict__ W2t,
    const float* __restrict__ b2,
    unsigned long long* __restrict__ win32,
    unsigned long long* __restrict__ win64,
    uint4* __restrict__ feat)
{
    const long gid = (long)blockIdx.x * 256 + threadIdx.x;  // over B*N
    const int b = (int)(gid >> kNLog);
    const int j = (int)(gid & (kN - 1));

    const float v0 = x[gid * 3 + 0];
    const float v1 = x[gid * 3 + 1];
    const float v2 = x[gid * 3 + 2];
    const unsigned int pri = (unsigned int)(inv[gid] + 1);

    const int ix32 = (int)fminf(fmaxf(__fadd_rn(__fmul_rn(v0, 32.0f), 16.5f), 0.0f), 31.0f);
    const int iy32 = (int)fminf(fmaxf(__fadd_rn(__fmul_rn(v1, 32.0f), 16.5f), 0.0f), 31.0f);
    const int iz32 = (int)fminf(fmaxf(__fadd_rn(__fmul_rn(v2, 32.0f), 16.5f), 0.0f), 31.0f);
    const int ix64 = (int)fminf(fmaxf(__fadd_rn(__fmul_rn(v0, 64.0f), 32.5f), 0.0f), 63.0f);
    const int iy64 = (int)fminf(fmaxf(__fadd_rn(__fmul_rn(v1, 64.0f), 32.5f), 0.0f), 63.0f);
    const int iz64 = (int)fminf(fmaxf(__fadd_rn(__fmul_rn(v2, 64.0f), 32.5f), 0.0f), 63.0f);

    const unsigned long long tok =
        ((unsigned long long)pri << 32) | (unsigned int)j;
    atomicMax(&win32[b * kCells32 + (ix32 * 32 + iy32) * 32 + iz32], tok);
    atomicMax(&win64[b * kCells64 + (ix64 * 64 + iy64) * 64 + iz64], tok);

    float acc[kCOut];
    #pragma unroll
    for (int c = 0; c < kCOut; ++c) acc[c] = 0.0f;

    const float4* __restrict__ w1v = (const float4*)W1p;
    const float4* __restrict__ w2v = (const float4*)W2t;

    #pragma unroll 4
    for (int k = 0; k < kCMid; ++k) {
        const float4 w1 = w1v[k];                        // uniform -> s_load
        const float h = fmaxf(fmaf(w1.x, v0, fmaf(w1.y, v1, fmaf(w1.z, v2, w1.w))), 0.0f);
        #pragma unroll
        for (int q = 0; q < 4; ++q) {
            const float4 wq = w2v[k * 4 + q];            // uniform -> s_load
            acc[4 * q + 0] = fmaf(wq.x, h, acc[4 * q + 0]);
            acc[4 * q + 1] = fmaf(wq.y, h, acc[4 * q + 1]);
            acc[4 * q + 2] = fmaf(wq.z, h, acc[4 * q + 2]);
            acc[4 * q + 3] = fmaf(wq.w, h, acc[4 * q + 3]);
        }
    }

    const float4 bq0 = ((const float4*)b2)[0];
    const float4 bq1 = ((const float4*)b2)[1];
    const float4 bq2 = ((const float4*)b2)[2];
    const float4 bq3 = ((const float4*)b2)[3];

    uint4 f;
    f.x = packbf2(acc[0]  + bq0.x, acc[1]  + bq0.y);
    f.y = packbf2(acc[2]  + bq0.z, acc[3]  + bq0.w);
    f.z = packbf2(acc[4]  + bq1.x, acc[5]  + bq1.y);
    f.w = packbf2(acc[6]  + bq1.z, acc[7]  + bq1.w);
    feat[gid * 2 + 0] = f;
    f.x = packbf2(acc[8]  + bq2.x, acc[9]  + bq2.y);
    f.y = packbf2(acc[10] + bq2.z, acc[11] + bq2.w);
    f.z = packbf2(acc[12] + bq3.x, acc[13] + bq3.y);
    f.w = packbf2(acc[14] + bq3.z, acc[15] + bq3.w);
    feat[gid * 2 + 1] = f;
}

// ---------------------------------------------------------------------------
// Per-cell gather: u64 win (coalesced 8B) -> j = low32 -> feat[b,j]
// (single random 32B hop), expand bf16 -> f32, write all 16 channels
// (zeros if empty). Rewrites the full output every call.
// ---------------------------------------------------------------------------
template <int CLOG>
__global__ __launch_bounds__(256) void k_gather(
    const unsigned long long* __restrict__ win,
    const uint4* __restrict__ feat,
    float* __restrict__ out)
{
    constexpr int cells = 1 << CLOG;
    const long gid = (long)blockIdx.x * 256 + threadIdx.x;  // over B*cells
    const int b = (int)(gid >> CLOG);
    const int cell = (int)(gid & (cells - 1));
    const unsigned long long w = win[gid];

    float v[kCOut];
    #pragma unroll
    for (int c = 0; c < kCOut; ++c) v[c] = 0.0f;

    if (w != 0ull) {
        const int j = (int)(w & 0xFFFFFFFFull);
        const long pidx = ((long)b << kNLog) + j;
        const uint4 f0 = feat[pidx * 2 + 0];
        const uint4 f1 = feat[pidx * 2 + 1];
        v[0]  = bf_lo(f0.x); v[1]  = bf_hi(f0.x);
        v[2]  = bf_lo(f0.y); v[3]  = bf_hi(f0.y);
        v[4]  = bf_lo(f0.z); v[5]  = bf_hi(f0.z);
        v[6]  = bf_lo(f0.w); v[7]  = bf_hi(f0.w);
        v[8]  = bf_lo(f1.x); v[9]  = bf_hi(f1.x);
        v[10] = bf_lo(f1.y); v[11] = bf_hi(f1.y);
        v[12] = bf_lo(f1.z); v[13] = bf_hi(f1.z);
        v[14] = bf_lo(f1.w); v[15] = bf_hi(f1.w);
    }

    float* op = out + (((long)b * kCOut) << CLOG) + cell;
    #pragma unroll
    for (int c = 0; c < kCOut; ++c) op[(long)c << CLOG] = v[c];
}

extern "C" void kernel_launch(void* const* d_in, const int* in_sizes, int n_in,
                              void* d_out, int out_size, void* d_ws, size_t ws_size,
                              hipStream_t stream)
{
    const float* x  = (const float*)d_in[0];
    const float* W1 = (const float*)d_in[1];
    const float* b1 = (const float*)d_in[2];
    const float* W2 = (const float*)d_in[3];
    const float* b2 = (const float*)d_in[4];
    const int* perm = (const int*)d_in[5];

    float* out32 = (float*)d_out;
    float* out64 = out32 + kOut32Elems;

    // ws layout:
    //  [W1p 2KB][W2t 8KB][pad->16KB]
    //  [win32 u64: 4.19MB][win64 u64: 33.55MB]
    //  [inv 8.39MB][feat 67.1MB]           total ~113 MB
    float* W1p = (float*)d_ws;
    float* W2t = W1p + kCMid * 4;
    unsigned long long* win32 = (unsigned long long*)((char*)d_ws + 16384);
    unsigned long long* win64 = win32 + (size_t)kB * kCells32;
    const size_t winBytes = (size_t)kB * (kCells32 + kCells64) * sizeof(unsigned long long);
    int* inv = (int*)((char*)win32 + winBytes);
    uint4* feat = (uint4*)(inv + (size_t)kB * kN);

    const int nPtsBlocks = (int)(((long)kB * kN) / 256);        // 8192
    const int n32Blocks  = (int)(((long)kB * kCells32) / 256);  // 2048
    const int n64Blocks  = (int)(((long)kB * kCells64) / 256);  // 16384
    dim3 blk(256);

    k_zero<<<2048, blk, 0, stream>>>((uint4*)win32);
    k_inv<<<nPtsBlocks, blk, 0, stream>>>(perm, inv);
    k_pack<<<1, 256, 0, stream>>>(W1, b1, W2, W1p, W2t);

    k_fused<<<nPtsBlocks, blk, 0, stream>>>(
        x, inv, W1p, W2t, b2, win32, win64, feat);

    k_gather<kCells32Log><<<n32Blocks, blk, 0, stream>>>(win32, feat, out32);
    k_gather<kCells64Log><<<n64Blocks, blk, 0, stream>>>(win64, feat, out64);
}